// Round 4
// baseline (277.432 us; speedup 1.0000x reference)
//
#include <hip/hip_runtime.h>
#include <math.h>

#define CUTOFF2 100.0f
#define EW_ALPHA 0.3f
#define SCREEN_BLOCKS 2048
#define PH2_BLOCKS 256
#define NT 256
#define LIST_CAP 262144   // 4 MB of float4; expected ~39k entries (6.7x margin)

// ws layout: [0:16) int count (+pad) | [16 : 16+LIST_CAP*16) float4 list |
//            [16+LIST_CAP*16 : +PH2_BLOCKS*8) double partials

__global__ void reset_kernel(int* count) {
    if (threadIdx.x == 0) *count = 0;
}

__global__ __launch_bounds__(NT)
void screen_kernel(const float* __restrict__ coords,
                   const float* __restrict__ box,
                   const int2* __restrict__ pairs,
                   float4* __restrict__ list,
                   int* __restrict__ count,
                   int n_pairs) {
    const float Lx = box[0], Ly = box[4], Lz = box[8];
    const float iLx = 1.0f / Lx, iLy = 1.0f / Ly, iLz = 1.0f / Lz;
    const int stride = gridDim.x * blockDim.x;
    for (int idx = blockIdx.x * blockDim.x + threadIdx.x; idx < n_pairs; idx += stride) {
        int2 pr = pairs[idx];
        int i = pr.x, j = pr.y;
        float dx = coords[3*j+0] - coords[3*i+0];
        float dy = coords[3*j+1] - coords[3*i+1];
        float dz = coords[3*j+2] - coords[3*i+2];
        float x = dx - rintf(dx * iLx) * Lx;
        float y = dy - rintf(dy * iLy) * Ly;
        float z = dz - rintf(dz * iLz) * Lz;
        float r2 = x*x + y*y + z*z;
        if (r2 <= CUTOFF2) {
            int slot = atomicAdd(count, 1);   // compiler wave-coalesces this
            if (slot < LIST_CAP)
                list[slot] = make_float4(x, y, z, __int_as_float(idx));
        }
    }
}

__global__ __launch_bounds__(NT)
void mp_dense_kernel(const float4* __restrict__ list,
                     const int* __restrict__ count,
                     const int2* __restrict__ pairs,
                     const float* __restrict__ q,
                     const float* __restrict__ p,
                     const float* __restrict__ t,
                     double* __restrict__ partial) {
    const float PREF = 1.1283791670955126f; // 2/sqrt(pi)
    int n = *count;
    if (n > LIST_CAP) n = LIST_CAP;

    double acc = 0.0;
    const int stride = gridDim.x * blockDim.x;
    for (int k = blockIdx.x * blockDim.x + threadIdx.x; k < n; k += stride) {
        float4 ent = list[k];
        float x = ent.x, y = ent.y, z = ent.z;
        int idx = __float_as_int(ent.w);
        int2 pr = pairs[idx];
        int i = pr.x, j = pr.y;

        float r2 = x*x + y*y + z*z;
        float r = sqrtf(r2);
        float rinv = 1.0f / r;

        float u  = EW_ALPHA * r;
        float u2 = u*u;
        float u3 = u2*u, u5 = u3*u2, u7 = u5*u2;
        float e2 = expf(-u2);
        float ec = erfcf(u);
        float d1 = ec;
        float d3 = ec + PREF * u * e2;
        float d5 = ec + PREF * ((3.0f*u + 2.0f*u3) * (1.0f/3.0f)) * e2;
        float d7 = ec + PREF * ((15.0f*u + 10.0f*u3 + 4.0f*u5) * (1.0f/15.0f)) * e2;
        float d9 = ec + PREF * ((105.0f*u + 70.0f*u3 + 28.0f*u5 + 8.0f*u7) * (1.0f/105.0f)) * e2;

        float ri2 = rinv * rinv;
        float r3i = rinv * ri2;
        float r5i = r3i * ri2;
        float r7i = r5i * ri2;
        float r9i = r7i * ri2;
        float R1 = rinv * d1;
        float R3 = r3i * d3;
        float R5 = r5i * d5;
        float R7 = r7i * d7;
        float R9 = r9i * d9;

        float x2 = x*x, y2 = y*y, z2 = z*z;
        float xy = x*y, xz = x*z, yz = y*z;

        float tx = -x * R3, ty = -y * R3, tz = -z * R3;
        float txx = 3.0f*x2*R5 - R3;
        float txy = 3.0f*xy*R5;
        float txz = 3.0f*xz*R5;
        float tyy = 3.0f*y2*R5 - R3;
        float tyz = 3.0f*yz*R5;
        float tzz = 3.0f*z2*R5 - R3;
        float txxx = x*(9.0f*R5 - 15.0f*x2*R7);
        float txxy = y*(3.0f*R5 - 15.0f*x2*R7);
        float txxz = z*(3.0f*R5 - 15.0f*x2*R7);
        float tyyy = y*(9.0f*R5 - 15.0f*y2*R7);
        float tyyx = x*(3.0f*R5 - 15.0f*y2*R7);
        float tyyz = z*(3.0f*R5 - 15.0f*y2*R7);
        float tzzz = z*(9.0f*R5 - 15.0f*z2*R7);
        float tzzx = x*(3.0f*R5 - 15.0f*z2*R7);
        float tzzy = y*(3.0f*R5 - 15.0f*z2*R7);
        float txyz = -15.0f*x*yz*R7;
        float txxxx = 105.0f*x2*x2*R9 - 90.0f*x2*R7 + 9.0f*R5;
        float txxxy = xy*(105.0f*x2*R9 - 45.0f*R7);
        float txxxz = xz*(105.0f*x2*R9 - 45.0f*R7);
        float txxyy = 105.0f*x2*y2*R9 - 15.0f*(x2+y2)*R7 + 3.0f*R5;
        float txxzz = 105.0f*x2*z2*R9 - 15.0f*(x2+z2)*R7 + 3.0f*R5;
        float txxyz = yz*(105.0f*x2*R9 - 15.0f*R7);
        float tyyyy = 105.0f*y2*y2*R9 - 90.0f*y2*R7 + 9.0f*R5;
        float tyyyx = xy*(105.0f*y2*R9 - 45.0f*R7);
        float tyyyz = yz*(105.0f*y2*R9 - 45.0f*R7);
        float tyyzz = 105.0f*y2*z2*R9 - 15.0f*(y2+z2)*R7 + 3.0f*R5;
        float tyyxz = xz*(105.0f*y2*R9 - 15.0f*R7);
        float tzzzz = 105.0f*z2*z2*R9 - 90.0f*z2*R7 + 9.0f*R5;
        float tzzzx = xz*(105.0f*z2*R9 - 45.0f*R7);
        float tzzzy = yz*(105.0f*z2*R9 - 45.0f*R7);
        float tzzxy = xy*(105.0f*z2*R9 - 15.0f*R7);

        const float* ti = t + 9*i;
        const float* tj = t + 9*j;
        float mi0 = q[i];
        float mi1 = p[3*i+0], mi2 = p[3*i+1], mi3 = p[3*i+2];
        float mi4 = ti[0] * (1.0f/3.0f);
        float mi5 = (ti[1] + ti[3]) * (1.0f/3.0f);
        float mi6 = (ti[2] + ti[6]) * (1.0f/3.0f);
        float mi7 = ti[4] * (1.0f/3.0f);
        float mi8 = (ti[5] + ti[7]) * (1.0f/3.0f);
        float mi9 = ti[8] * (1.0f/3.0f);
        float mj0 = q[j];
        float mj1 = p[3*j+0], mj2 = p[3*j+1], mj3 = p[3*j+2];
        float mj4 = tj[0] * (1.0f/3.0f);
        float mj5 = (tj[1] + tj[3]) * (1.0f/3.0f);
        float mj6 = (tj[2] + tj[6]) * (1.0f/3.0f);
        float mj7 = tj[4] * (1.0f/3.0f);
        float mj8 = (tj[5] + tj[7]) * (1.0f/3.0f);
        float mj9 = tj[8] * (1.0f/3.0f);

        float E0 = R1*mi0  - tx*mi1   - ty*mi2   - tz*mi3   + txx*mi4   + txy*mi5   + txz*mi6   + tyy*mi7   + tyz*mi8   + tzz*mi9;
        float E1 = tx*mi0  - txx*mi1  - txy*mi2  - txz*mi3  + txxx*mi4  + txxy*mi5  + txxz*mi6  + tyyx*mi7  + txyz*mi8  + tzzx*mi9;
        float E2 = ty*mi0  - txy*mi1  - tyy*mi2  - tyz*mi3  + txxy*mi4  + tyyx*mi5  + txyz*mi6  + tyyy*mi7  + tyyz*mi8  + tzzy*mi9;
        float E3 = tz*mi0  - txz*mi1  - tyz*mi2  - tzz*mi3  + txxz*mi4  + txyz*mi5  + tzzx*mi6  + tyyz*mi7  + tzzy*mi8  + tzzz*mi9;
        float E4 = txx*mi0 - txxx*mi1 - txxy*mi2 - txxz*mi3 + txxxx*mi4 + txxxy*mi5 + txxxz*mi6 + txxyy*mi7 + txxyz*mi8 + txxzz*mi9;
        float E5 = txy*mi0 - txxy*mi1 - tyyx*mi2 - txyz*mi3 + txxxy*mi4 + txxyy*mi5 + txxyz*mi6 + tyyyx*mi7 + tyyxz*mi8 + tzzxy*mi9;
        float E6 = txz*mi0 - txxz*mi1 - txyz*mi2 - tzzx*mi3 + txxxz*mi4 + txxyz*mi5 + txxzz*mi6 + tyyxz*mi7 + tzzxy*mi8 + tzzzx*mi9;
        float E7 = tyy*mi0 - tyyx*mi1 - tyyy*mi2 - tyyz*mi3 + txxyy*mi4 + tyyyx*mi5 + tyyxz*mi6 + tyyyy*mi7 + tyyyz*mi8 + tyyzz*mi9;
        float E8 = tyz*mi0 - txyz*mi1 - tyyz*mi2 - tzzy*mi3 + txxyz*mi4 + tyyxz*mi5 + tzzxy*mi6 + tyyyz*mi7 + tyyzz*mi8 + tzzzy*mi9;
        float E9 = tzz*mi0 - tzzx*mi1 - tzzy*mi2 - tzzz*mi3 + txxzz*mi4 + tzzxy*mi5 + tzzzx*mi6 + tyyzz*mi7 + tzzzy*mi8 + tzzzz*mi9;

        float e = mj0*E0 + mj1*E1 + mj2*E2 + mj3*E3 + mj4*E4
                + mj5*E5 + mj6*E6 + mj7*E7 + mj8*E8 + mj9*E9;

        acc += (double)e;
    }

    __shared__ double sdata[NT];
    int tid = threadIdx.x;
    sdata[tid] = acc;
    __syncthreads();
    for (int s = NT/2; s > 0; s >>= 1) {
        if (tid < s) sdata[tid] += sdata[tid + s];
        __syncthreads();
    }
    if (tid == 0) partial[blockIdx.x] = sdata[0];  // unconditional: overwrites stale ws
}

__global__ __launch_bounds__(256)
void mp_reduce_kernel(const double* __restrict__ partial, int n, float* __restrict__ out) {
    __shared__ double sdata[256];
    int tid = threadIdx.x;
    double a = 0.0;
    for (int i = tid; i < n; i += 256) a += partial[i];
    sdata[tid] = a;
    __syncthreads();
    for (int s = 128; s > 0; s >>= 1) {
        if (tid < s) sdata[tid] += sdata[tid + s];
        __syncthreads();
    }
    if (tid == 0) out[0] = (float)sdata[0];
}

extern "C" void kernel_launch(void* const* d_in, const int* in_sizes, int n_in,
                              void* d_out, int out_size, void* d_ws, size_t ws_size,
                              hipStream_t stream) {
    const float* coords = (const float*)d_in[0];
    const float* box    = (const float*)d_in[1];
    const int2*  pairs  = (const int2*)d_in[2];
    const float* q      = (const float*)d_in[3];
    const float* p      = (const float*)d_in[4];
    const float* t      = (const float*)d_in[5];
    int n_pairs = in_sizes[2] / 2;

    char* ws = (char*)d_ws;
    int*    count   = (int*)ws;
    float4* list    = (float4*)(ws + 16);
    double* partial = (double*)(ws + 16 + (size_t)LIST_CAP * sizeof(float4));

    reset_kernel<<<1, 64, 0, stream>>>(count);
    screen_kernel<<<SCREEN_BLOCKS, NT, 0, stream>>>(coords, box, pairs, list, count, n_pairs);
    mp_dense_kernel<<<PH2_BLOCKS, NT, 0, stream>>>(list, count, pairs, q, p, t, partial);
    mp_reduce_kernel<<<1, 256, 0, stream>>>(partial, PH2_BLOCKS, (float*)d_out);
}

// Round 5
// 36.989 us; speedup vs baseline: 7.5003x; 7.5003x over previous
//
#include <hip/hip_runtime.h>
#include <math.h>

#define CUTOFF2 100.0f
#define EW_ALPHA 0.3f
#define SEGS 2048
#define NT 256
#define CAP 128   // per-segment survivor capacity (mean ~19, 25-sigma margin)

// ws layout: [0 : 8KB) int counts[SEGS] | [8KB : 8KB+4MB) float4 list[SEGS*CAP]
//            | [+ : +16KB) double partial[SEGS]

__global__ __launch_bounds__(NT)
void screen_kernel(const float* __restrict__ coords,
                   const float* __restrict__ box,
                   const int2* __restrict__ pairs,
                   float4* __restrict__ list,
                   int* __restrict__ counts,
                   int n_pairs, int chunk) {
    __shared__ int lcount;
    if (threadIdx.x == 0) lcount = 0;
    __syncthreads();

    const float Lx = box[0], Ly = box[4], Lz = box[8];
    const float iLx = 1.0f / Lx, iLy = 1.0f / Ly, iLz = 1.0f / Lz;

    const int b = blockIdx.x;
    const int start = b * chunk;
    const int end = min(start + chunk, n_pairs);
    for (int idx = start + threadIdx.x; idx < end; idx += NT) {
        int2 pr = pairs[idx];
        int i = pr.x, j = pr.y;
        float dx = coords[3*j+0] - coords[3*i+0];
        float dy = coords[3*j+1] - coords[3*i+1];
        float dz = coords[3*j+2] - coords[3*i+2];
        float x = dx - rintf(dx * iLx) * Lx;
        float y = dy - rintf(dy * iLy) * Ly;
        float z = dz - rintf(dz * iLz) * Lz;
        float r2 = x*x + y*y + z*z;
        if (r2 <= CUTOFF2) {
            int slot = atomicAdd(&lcount, 1);   // LDS atomic: fast, block-local
            if (slot < CAP)
                list[b*CAP + slot] = make_float4(x, y, z, __int_as_float(idx));
        }
    }
    __syncthreads();
    if (threadIdx.x == 0) counts[b] = min(lcount, CAP);
}

__global__ __launch_bounds__(NT)
void mp_dense_kernel(const float4* __restrict__ list,
                     const int* __restrict__ counts,
                     const int2* __restrict__ pairs,
                     const float* __restrict__ q,
                     const float* __restrict__ p,
                     const float* __restrict__ t,
                     double* __restrict__ partial) {
    const float PREF = 1.1283791670955126f; // 2/sqrt(pi)
    const int b = blockIdx.x;
    const int n = counts[b];

    double acc = 0.0;
    for (int k = threadIdx.x; k < n; k += NT) {
        float4 ent = list[b*CAP + k];
        float x = ent.x, y = ent.y, z = ent.z;
        int idx = __float_as_int(ent.w);
        int2 pr = pairs[idx];
        int i = pr.x, j = pr.y;

        float r2 = x*x + y*y + z*z;
        float r = sqrtf(r2);
        float rinv = 1.0f / r;

        float u  = EW_ALPHA * r;
        float u2 = u*u;
        float u3 = u2*u, u5 = u3*u2, u7 = u5*u2;
        float e2 = expf(-u2);
        float ec = erfcf(u);
        float d1 = ec;
        float d3 = ec + PREF * u * e2;
        float d5 = ec + PREF * ((3.0f*u + 2.0f*u3) * (1.0f/3.0f)) * e2;
        float d7 = ec + PREF * ((15.0f*u + 10.0f*u3 + 4.0f*u5) * (1.0f/15.0f)) * e2;
        float d9 = ec + PREF * ((105.0f*u + 70.0f*u3 + 28.0f*u5 + 8.0f*u7) * (1.0f/105.0f)) * e2;

        float ri2 = rinv * rinv;
        float r3i = rinv * ri2;
        float r5i = r3i * ri2;
        float r7i = r5i * ri2;
        float r9i = r7i * ri2;
        float R1 = rinv * d1;
        float R3 = r3i * d3;
        float R5 = r5i * d5;
        float R7 = r7i * d7;
        float R9 = r9i * d9;

        float x2 = x*x, y2 = y*y, z2 = z*z;
        float xy = x*y, xz = x*z, yz = y*z;

        float tx = -x * R3, ty = -y * R3, tz = -z * R3;
        float txx = 3.0f*x2*R5 - R3;
        float txy = 3.0f*xy*R5;
        float txz = 3.0f*xz*R5;
        float tyy = 3.0f*y2*R5 - R3;
        float tyz = 3.0f*yz*R5;
        float tzz = 3.0f*z2*R5 - R3;
        float txxx = x*(9.0f*R5 - 15.0f*x2*R7);
        float txxy = y*(3.0f*R5 - 15.0f*x2*R7);
        float txxz = z*(3.0f*R5 - 15.0f*x2*R7);
        float tyyy = y*(9.0f*R5 - 15.0f*y2*R7);
        float tyyx = x*(3.0f*R5 - 15.0f*y2*R7);
        float tyyz = z*(3.0f*R5 - 15.0f*y2*R7);
        float tzzz = z*(9.0f*R5 - 15.0f*z2*R7);
        float tzzx = x*(3.0f*R5 - 15.0f*z2*R7);
        float tzzy = y*(3.0f*R5 - 15.0f*z2*R7);
        float txyz = -15.0f*x*yz*R7;
        float txxxx = 105.0f*x2*x2*R9 - 90.0f*x2*R7 + 9.0f*R5;
        float txxxy = xy*(105.0f*x2*R9 - 45.0f*R7);
        float txxxz = xz*(105.0f*x2*R9 - 45.0f*R7);
        float txxyy = 105.0f*x2*y2*R9 - 15.0f*(x2+y2)*R7 + 3.0f*R5;
        float txxzz = 105.0f*x2*z2*R9 - 15.0f*(x2+z2)*R7 + 3.0f*R5;
        float txxyz = yz*(105.0f*x2*R9 - 15.0f*R7);
        float tyyyy = 105.0f*y2*y2*R9 - 90.0f*y2*R7 + 9.0f*R5;
        float tyyyx = xy*(105.0f*y2*R9 - 45.0f*R7);
        float tyyyz = yz*(105.0f*y2*R9 - 45.0f*R7);
        float tyyzz = 105.0f*y2*z2*R9 - 15.0f*(y2+z2)*R7 + 3.0f*R5;
        float tyyxz = xz*(105.0f*y2*R9 - 15.0f*R7);
        float tzzzz = 105.0f*z2*z2*R9 - 90.0f*z2*R7 + 9.0f*R5;
        float tzzzx = xz*(105.0f*z2*R9 - 45.0f*R7);
        float tzzzy = yz*(105.0f*z2*R9 - 45.0f*R7);
        float tzzxy = xy*(105.0f*z2*R9 - 15.0f*R7);

        const float* ti = t + 9*i;
        const float* tj = t + 9*j;
        float mi0 = q[i];
        float mi1 = p[3*i+0], mi2 = p[3*i+1], mi3 = p[3*i+2];
        float mi4 = ti[0] * (1.0f/3.0f);
        float mi5 = (ti[1] + ti[3]) * (1.0f/3.0f);
        float mi6 = (ti[2] + ti[6]) * (1.0f/3.0f);
        float mi7 = ti[4] * (1.0f/3.0f);
        float mi8 = (ti[5] + ti[7]) * (1.0f/3.0f);
        float mi9 = ti[8] * (1.0f/3.0f);
        float mj0 = q[j];
        float mj1 = p[3*j+0], mj2 = p[3*j+1], mj3 = p[3*j+2];
        float mj4 = tj[0] * (1.0f/3.0f);
        float mj5 = (tj[1] + tj[3]) * (1.0f/3.0f);
        float mj6 = (tj[2] + tj[6]) * (1.0f/3.0f);
        float mj7 = tj[4] * (1.0f/3.0f);
        float mj8 = (tj[5] + tj[7]) * (1.0f/3.0f);
        float mj9 = tj[8] * (1.0f/3.0f);

        float E0 = R1*mi0  - tx*mi1   - ty*mi2   - tz*mi3   + txx*mi4   + txy*mi5   + txz*mi6   + tyy*mi7   + tyz*mi8   + tzz*mi9;
        float E1 = tx*mi0  - txx*mi1  - txy*mi2  - txz*mi3  + txxx*mi4  + txxy*mi5  + txxz*mi6  + tyyx*mi7  + txyz*mi8  + tzzx*mi9;
        float E2 = ty*mi0  - txy*mi1  - tyy*mi2  - tyz*mi3  + txxy*mi4  + tyyx*mi5  + txyz*mi6  + tyyy*mi7  + tyyz*mi8  + tzzy*mi9;
        float E3 = tz*mi0  - txz*mi1  - tyz*mi2  - tzz*mi3  + txxz*mi4  + txyz*mi5  + tzzx*mi6  + tyyz*mi7  + tzzy*mi8  + tzzz*mi9;
        float E4 = txx*mi0 - txxx*mi1 - txxy*mi2 - txxz*mi3 + txxxx*mi4 + txxxy*mi5 + txxxz*mi6 + txxyy*mi7 + txxyz*mi8 + txxzz*mi9;
        float E5 = txy*mi0 - txxy*mi1 - tyyx*mi2 - txyz*mi3 + txxxy*mi4 + txxyy*mi5 + txxyz*mi6 + tyyyx*mi7 + tyyxz*mi8 + tzzxy*mi9;
        float E6 = txz*mi0 - txxz*mi1 - txyz*mi2 - tzzx*mi3 + txxxz*mi4 + txxyz*mi5 + txxzz*mi6 + tyyxz*mi7 + tzzxy*mi8 + tzzzx*mi9;
        float E7 = tyy*mi0 - tyyx*mi1 - tyyy*mi2 - tyyz*mi3 + txxyy*mi4 + tyyyx*mi5 + tyyxz*mi6 + tyyyy*mi7 + tyyyz*mi8 + tyyzz*mi9;
        float E8 = tyz*mi0 - txyz*mi1 - tyyz*mi2 - tzzy*mi3 + txxyz*mi4 + tyyxz*mi5 + tzzxy*mi6 + tyyyz*mi7 + tyyzz*mi8 + tzzzy*mi9;
        float E9 = tzz*mi0 - tzzx*mi1 - tzzy*mi2 - tzzz*mi3 + txxzz*mi4 + tzzxy*mi5 + tzzzx*mi6 + tyyzz*mi7 + tzzzy*mi8 + tzzzz*mi9;

        float e = mj0*E0 + mj1*E1 + mj2*E2 + mj3*E3 + mj4*E4
                + mj5*E5 + mj6*E6 + mj7*E7 + mj8*E8 + mj9*E9;

        acc += (double)e;
    }

    __shared__ double sdata[NT];
    int tid = threadIdx.x;
    sdata[tid] = acc;
    __syncthreads();
    for (int s = NT/2; s > 0; s >>= 1) {
        if (tid < s) sdata[tid] += sdata[tid + s];
        __syncthreads();
    }
    if (tid == 0) partial[b] = sdata[0];  // unconditional: overwrites stale ws
}

__global__ __launch_bounds__(256)
void mp_reduce_kernel(const double* __restrict__ partial, int n, float* __restrict__ out) {
    __shared__ double sdata[256];
    int tid = threadIdx.x;
    double a = 0.0;
    for (int i = tid; i < n; i += 256) a += partial[i];
    sdata[tid] = a;
    __syncthreads();
    for (int s = 128; s > 0; s >>= 1) {
        if (tid < s) sdata[tid] += sdata[tid + s];
        __syncthreads();
    }
    if (tid == 0) out[0] = (float)sdata[0];
}

extern "C" void kernel_launch(void* const* d_in, const int* in_sizes, int n_in,
                              void* d_out, int out_size, void* d_ws, size_t ws_size,
                              hipStream_t stream) {
    const float* coords = (const float*)d_in[0];
    const float* box    = (const float*)d_in[1];
    const int2*  pairs  = (const int2*)d_in[2];
    const float* q      = (const float*)d_in[3];
    const float* p      = (const float*)d_in[4];
    const float* t      = (const float*)d_in[5];
    int n_pairs = in_sizes[2] / 2;
    int chunk = (n_pairs + SEGS - 1) / SEGS;

    char* ws = (char*)d_ws;
    int*    counts  = (int*)ws;
    float4* list    = (float4*)(ws + SEGS * sizeof(int));
    double* partial = (double*)(ws + SEGS * sizeof(int) + (size_t)SEGS * CAP * sizeof(float4));

    screen_kernel<<<SEGS, NT, 0, stream>>>(coords, box, pairs, list, counts, n_pairs, chunk);
    mp_dense_kernel<<<SEGS, NT, 0, stream>>>(list, counts, pairs, q, p, t, partial);
    mp_reduce_kernel<<<1, 256, 0, stream>>>(partial, SEGS, (float*)d_out);
}

// Round 6
// 35.442 us; speedup vs baseline: 7.8279x; 1.0437x over previous
//
#include <hip/hip_runtime.h>
#include <math.h>

#define CUTOFF2 100.0f
#define EW_ALPHA 0.3f
#define SEGS 2048
#define NT 256
#define CAP 96   // per-block survivor capacity (mean ~19, sigma ~4.3 -> 17-sigma margin)

__device__ __forceinline__ double pair_energy(float x, float y, float z,
                                              int i, int j,
                                              const float* __restrict__ q,
                                              const float* __restrict__ p,
                                              const float* __restrict__ t) {
    const float PREF = 1.1283791670955126f; // 2/sqrt(pi)
    float r2 = x*x + y*y + z*z;
    float r = sqrtf(r2);
    float rinv = 1.0f / r;

    float u  = EW_ALPHA * r;
    float u2 = u*u;
    float u3 = u2*u, u5 = u3*u2, u7 = u5*u2;
    float e2 = expf(-u2);
    float ec = erfcf(u);
    float d1 = ec;
    float d3 = ec + PREF * u * e2;
    float d5 = ec + PREF * ((3.0f*u + 2.0f*u3) * (1.0f/3.0f)) * e2;
    float d7 = ec + PREF * ((15.0f*u + 10.0f*u3 + 4.0f*u5) * (1.0f/15.0f)) * e2;
    float d9 = ec + PREF * ((105.0f*u + 70.0f*u3 + 28.0f*u5 + 8.0f*u7) * (1.0f/105.0f)) * e2;

    float ri2 = rinv * rinv;
    float r3i = rinv * ri2;
    float r5i = r3i * ri2;
    float r7i = r5i * ri2;
    float r9i = r7i * ri2;
    float R1 = rinv * d1;
    float R3 = r3i * d3;
    float R5 = r5i * d5;
    float R7 = r7i * d7;
    float R9 = r9i * d9;

    float x2 = x*x, y2 = y*y, z2 = z*z;
    float xy = x*y, xz = x*z, yz = y*z;

    float tx = -x * R3, ty = -y * R3, tz = -z * R3;
    float txx = 3.0f*x2*R5 - R3;
    float txy = 3.0f*xy*R5;
    float txz = 3.0f*xz*R5;
    float tyy = 3.0f*y2*R5 - R3;
    float tyz = 3.0f*yz*R5;
    float tzz = 3.0f*z2*R5 - R3;
    float txxx = x*(9.0f*R5 - 15.0f*x2*R7);
    float txxy = y*(3.0f*R5 - 15.0f*x2*R7);
    float txxz = z*(3.0f*R5 - 15.0f*x2*R7);
    float tyyy = y*(9.0f*R5 - 15.0f*y2*R7);
    float tyyx = x*(3.0f*R5 - 15.0f*y2*R7);
    float tyyz = z*(3.0f*R5 - 15.0f*y2*R7);
    float tzzz = z*(9.0f*R5 - 15.0f*z2*R7);
    float tzzx = x*(3.0f*R5 - 15.0f*z2*R7);
    float tzzy = y*(3.0f*R5 - 15.0f*z2*R7);
    float txyz = -15.0f*x*yz*R7;
    float txxxx = 105.0f*x2*x2*R9 - 90.0f*x2*R7 + 9.0f*R5;
    float txxxy = xy*(105.0f*x2*R9 - 45.0f*R7);
    float txxxz = xz*(105.0f*x2*R9 - 45.0f*R7);
    float txxyy = 105.0f*x2*y2*R9 - 15.0f*(x2+y2)*R7 + 3.0f*R5;
    float txxzz = 105.0f*x2*z2*R9 - 15.0f*(x2+z2)*R7 + 3.0f*R5;
    float txxyz = yz*(105.0f*x2*R9 - 15.0f*R7);
    float tyyyy = 105.0f*y2*y2*R9 - 90.0f*y2*R7 + 9.0f*R5;
    float tyyyx = xy*(105.0f*y2*R9 - 45.0f*R7);
    float tyyyz = yz*(105.0f*y2*R9 - 45.0f*R7);
    float tyyzz = 105.0f*y2*z2*R9 - 15.0f*(y2+z2)*R7 + 3.0f*R5;
    float tyyxz = xz*(105.0f*y2*R9 - 15.0f*R7);
    float tzzzz = 105.0f*z2*z2*R9 - 90.0f*z2*R7 + 9.0f*R5;
    float tzzzx = xz*(105.0f*z2*R9 - 45.0f*R7);
    float tzzzy = yz*(105.0f*z2*R9 - 45.0f*R7);
    float tzzxy = xy*(105.0f*z2*R9 - 15.0f*R7);

    const float* ti = t + 9*i;
    const float* tj = t + 9*j;
    float mi0 = q[i];
    float mi1 = p[3*i+0], mi2 = p[3*i+1], mi3 = p[3*i+2];
    float mi4 = ti[0] * (1.0f/3.0f);
    float mi5 = (ti[1] + ti[3]) * (1.0f/3.0f);
    float mi6 = (ti[2] + ti[6]) * (1.0f/3.0f);
    float mi7 = ti[4] * (1.0f/3.0f);
    float mi8 = (ti[5] + ti[7]) * (1.0f/3.0f);
    float mi9 = ti[8] * (1.0f/3.0f);
    float mj0 = q[j];
    float mj1 = p[3*j+0], mj2 = p[3*j+1], mj3 = p[3*j+2];
    float mj4 = tj[0] * (1.0f/3.0f);
    float mj5 = (tj[1] + tj[3]) * (1.0f/3.0f);
    float mj6 = (tj[2] + tj[6]) * (1.0f/3.0f);
    float mj7 = tj[4] * (1.0f/3.0f);
    float mj8 = (tj[5] + tj[7]) * (1.0f/3.0f);
    float mj9 = tj[8] * (1.0f/3.0f);

    float E0 = R1*mi0  - tx*mi1   - ty*mi2   - tz*mi3   + txx*mi4   + txy*mi5   + txz*mi6   + tyy*mi7   + tyz*mi8   + tzz*mi9;
    float E1 = tx*mi0  - txx*mi1  - txy*mi2  - txz*mi3  + txxx*mi4  + txxy*mi5  + txxz*mi6  + tyyx*mi7  + txyz*mi8  + tzzx*mi9;
    float E2 = ty*mi0  - txy*mi1  - tyy*mi2  - tyz*mi3  + txxy*mi4  + tyyx*mi5  + txyz*mi6  + tyyy*mi7  + tyyz*mi8  + tzzy*mi9;
    float E3 = tz*mi0  - txz*mi1  - tyz*mi2  - tzz*mi3  + txxz*mi4  + txyz*mi5  + tzzx*mi6  + tyyz*mi7  + tzzy*mi8  + tzzz*mi9;
    float E4 = txx*mi0 - txxx*mi1 - txxy*mi2 - txxz*mi3 + txxxx*mi4 + txxxy*mi5 + txxxz*mi6 + txxyy*mi7 + txxyz*mi8 + txxzz*mi9;
    float E5 = txy*mi0 - txxy*mi1 - tyyx*mi2 - txyz*mi3 + txxxy*mi4 + txxyy*mi5 + txxyz*mi6 + tyyyx*mi7 + tyyxz*mi8 + tzzxy*mi9;
    float E6 = txz*mi0 - txxz*mi1 - txyz*mi2 - tzzx*mi3 + txxxz*mi4 + txxyz*mi5 + txxzz*mi6 + tyyxz*mi7 + tzzxy*mi8 + tzzzx*mi9;
    float E7 = tyy*mi0 - tyyx*mi1 - tyyy*mi2 - tyyz*mi3 + txxyy*mi4 + tyyyx*mi5 + tyyxz*mi6 + tyyyy*mi7 + tyyyz*mi8 + tyyzz*mi9;
    float E8 = tyz*mi0 - txyz*mi1 - tyyz*mi2 - tzzy*mi3 + txxyz*mi4 + tyyxz*mi5 + tzzxy*mi6 + tyyyz*mi7 + tyyzz*mi8 + tzzzy*mi9;
    float E9 = tzz*mi0 - tzzx*mi1 - tzzy*mi2 - tzzz*mi3 + txxzz*mi4 + tzzxy*mi5 + tzzzx*mi6 + tyyzz*mi7 + tzzzy*mi8 + tzzzz*mi9;

    float e = mj0*E0 + mj1*E1 + mj2*E2 + mj3*E3 + mj4*E4
            + mj5*E5 + mj6*E6 + mj7*E7 + mj8*E8 + mj9*E9;
    return (double)e;
}

__global__ __launch_bounds__(NT)
void mp_fused_kernel(const float* __restrict__ coords,
                     const float* __restrict__ box,
                     const long long* __restrict__ pairs,
                     const float* __restrict__ q,
                     const float* __restrict__ p,
                     const float* __restrict__ t,
                     double* __restrict__ partial,
                     int n_pairs, int chunk) {
    __shared__ float sx[CAP], sy[CAP], sz[CAP];
    __shared__ int   si[CAP], sj[CAP];
    __shared__ int   scount;
    if (threadIdx.x == 0) scount = 0;
    __syncthreads();

    const float Lx = box[0], Ly = box[4], Lz = box[8];
    const float iLx = 1.0f / Lx, iLy = 1.0f / Ly, iLz = 1.0f / Lz;

    const int b = blockIdx.x;
    const int start = b * chunk;
    const int end = min(start + chunk, n_pairs);

    // Phase A: screen; compact survivors into LDS
    for (int idx = start + threadIdx.x; idx < end; idx += NT) {
        long long v = __builtin_nontemporal_load(pairs + idx);
        int i = (int)(v & 0xffffffffLL);
        int j = (int)(v >> 32);
        float dx = coords[3*j+0] - coords[3*i+0];
        float dy = coords[3*j+1] - coords[3*i+1];
        float dz = coords[3*j+2] - coords[3*i+2];
        float x = dx - rintf(dx * iLx) * Lx;
        float y = dy - rintf(dy * iLy) * Ly;
        float z = dz - rintf(dz * iLz) * Lz;
        float r2 = x*x + y*y + z*z;
        if (r2 <= CUTOFF2) {
            int slot = atomicAdd(&scount, 1);   // LDS atomic, block-local
            if (slot < CAP) {
                sx[slot] = x; sy[slot] = y; sz[slot] = z;
                si[slot] = i; sj[slot] = j;
            }
        }
    }
    __syncthreads();

    // Phase B: dense heavy path on survivors (lanes 0..ns-1 of the block)
    int ns = min(scount, CAP);
    double acc = 0.0;
    for (int k = threadIdx.x; k < ns; k += NT) {
        acc += pair_energy(sx[k], sy[k], sz[k], si[k], sj[k], q, p, t);
    }

    // block reduction (fixed tree order)
    __shared__ double sdata[NT];
    int tid = threadIdx.x;
    sdata[tid] = acc;
    __syncthreads();
    for (int s = NT/2; s > 0; s >>= 1) {
        if (tid < s) sdata[tid] += sdata[tid + s];
        __syncthreads();
    }
    if (tid == 0) partial[b] = sdata[0];   // unconditional: overwrites stale ws
}

__global__ __launch_bounds__(256)
void mp_reduce_kernel(const double* __restrict__ partial, int n, float* __restrict__ out) {
    __shared__ double sdata[256];
    int tid = threadIdx.x;
    double a = 0.0;
    for (int i = tid; i < n; i += 256) a += partial[i];
    sdata[tid] = a;
    __syncthreads();
    for (int s = 128; s > 0; s >>= 1) {
        if (tid < s) sdata[tid] += sdata[tid + s];
        __syncthreads();
    }
    if (tid == 0) out[0] = (float)sdata[0];
}

extern "C" void kernel_launch(void* const* d_in, const int* in_sizes, int n_in,
                              void* d_out, int out_size, void* d_ws, size_t ws_size,
                              hipStream_t stream) {
    const float*     coords = (const float*)d_in[0];
    const float*     box    = (const float*)d_in[1];
    const long long* pairs  = (const long long*)d_in[2];  // int2 pairs read as i64
    const float*     q      = (const float*)d_in[3];
    const float*     p      = (const float*)d_in[4];
    const float*     t      = (const float*)d_in[5];
    int n_pairs = in_sizes[2] / 2;
    int chunk = (n_pairs + SEGS - 1) / SEGS;

    double* partial = (double*)d_ws;

    mp_fused_kernel<<<SEGS, NT, 0, stream>>>(coords, box, pairs, q, p, t,
                                             partial, n_pairs, chunk);
    mp_reduce_kernel<<<1, 256, 0, stream>>>(partial, SEGS, (float*)d_out);
}